// Round 7
// baseline (11150.217 us; speedup 1.0000x reference)
//
#include <hip/hip_runtime.h>
#include <stdint.h>

// ---------- helpers ----------
__device__ __forceinline__ float bf2f(uint16_t v){ return __uint_as_float(((uint32_t)v) << 16); }
__device__ __forceinline__ uint16_t f2bf(float x){
  uint32_t u = __float_as_uint(x);
  return (uint16_t)((u + 0x7fffu + ((u >> 16) & 1u)) >> 16);
}
__device__ __forceinline__ float sigf(float x){
  float cx = fminf(fmaxf(x, -88.f), 88.f);     // exact for |x|<88; scrubs NaN
  return 1.f/(1.f + expf(-cx));
}
__device__ __forceinline__ float tanh_s(float x){
  float cx = fminf(fmaxf(x, -44.f), 44.f);
  return tanhf(cx);
}
// fast variants for the hot recurrent kernels (v_exp_f32-based, ~1e-7 rel err)
__device__ __forceinline__ float fast_sig(float x){
  float cx = fminf(fmaxf(x, -60.f), 60.f);
  return 1.f/(1.f + __expf(-cx));
}
__device__ __forceinline__ float fast_tanh(float x){
  float cx = fminf(fmaxf(x, -15.f), 15.f);
  float e = __expf(2.f*cx);
  return (e - 1.f)/(e + 1.f);
}

// ---------- workspace layout (bytes) — total ~22.6 MB ----------
static const size_t OFF_STATS = 0;            // 768 fp32
static const size_t OFF_FLAG  = 3072;         // 1 int (1 = fp32 inputs, 0 = bf16)
static const size_t OFF_AB    = 4096;         // 768 fp32
static const size_t OFF_P2R   = 8192;         // 2048*64*25 fp32 = 13107200
static const size_t OFF_Y3    = 13115392;     // 2048*576 fp32 = 4718592
static const size_t OFF_F     = 17833984;     // 2048*64 fp32
static const size_t OFF_XI    = 18358272;     // 2*1024*256 fp32
static const size_t OFF_XATT  = 20455424;     // 1024*256 fp32
static const size_t OFF_CA    = 21504000;
static const size_t OFF_CB    = 21766144;
static const size_t OFF_COND  = 22028288;
static const size_t OFF_NC    = 22290432;
static const size_t OFF_CT    = 22294528;     // ends 22556672

// ---------- sniff input dtype + zero stats ----------
__global__ void k_sniff(const uint32_t* im, float* stats, int* flag){
  int t = threadIdx.x;
  for (int i = t; i < 768; i += 256) stats[i] = 0.f;
  if (t < 64){
    uint32_t w = im[t];
    uint32_t e = (w >> 7) & 0xffu;             // exponent of low-half-as-bf16
    bool sane = (e >= 100u && e <= 140u);      // N(0,1) bf16 exponents land here
    unsigned long long m = __ballot(sane);
    if (t == 0) flag[0] = (__popcll(m) < 48) ? 1 : 0;   // junk exponents => fp32 data
  }
}

// ---------- conv1 stats ----------
__global__ __launch_bounds__(256) void k_conv1_stats(const void* im0, const void* im1,
        const void* w1, const void* b1, float* stats, const int* flag){
  __shared__ float xs[784];
  __shared__ float wl[576];
  __shared__ float bl1[64];
  __shared__ float rs[256], rq[256];
  int img = blockIdx.x;
  bool f32 = flag[0] != 0;
  if (f32){
    const float* im = (img < 1024) ? ((const float*)im0 + img*784) : ((const float*)im1 + (img-1024)*784);
    for (int i = threadIdx.x; i < 784; i += 256) xs[i] = im[i];
    for (int i = threadIdx.x; i < 576; i += 256) wl[i] = ((const float*)w1)[i];
    if (threadIdx.x < 64) bl1[threadIdx.x] = ((const float*)b1)[threadIdx.x];
  } else {
    const uint16_t* im = (img < 1024) ? ((const uint16_t*)im0 + img*784) : ((const uint16_t*)im1 + (img-1024)*784);
    for (int i = threadIdx.x; i < 784; i += 256) xs[i] = bf2f(im[i]);
    for (int i = threadIdx.x; i < 576; i += 256) wl[i] = bf2f(((const uint16_t*)w1)[i]);
    if (threadIdx.x < 64) bl1[threadIdx.x] = bf2f(((const uint16_t*)b1)[threadIdx.x]);
  }
  __syncthreads();
  int c = threadIdx.x & 63, pg = threadIdx.x >> 6;
  float w[9];
  #pragma unroll
  for (int k = 0; k < 9; k++) w[k] = wl[c*9+k];
  float bias = bl1[c];
  float s = 0.f, q = 0.f;
  for (int pos = pg; pos < 676; pos += 4){
    int y = pos/26, x = pos - y*26;
    const float* p = xs + y*28 + x;
    float acc = bias;
    #pragma unroll
    for (int dy = 0; dy < 3; dy++)
      #pragma unroll
      for (int dx = 0; dx < 3; dx++)
        acc += w[dy*3+dx]*p[dy*28+dx];
    s += acc; q += acc*acc;
  }
  rs[threadIdx.x] = s; rq[threadIdx.x] = q;
  __syncthreads();
  if (threadIdx.x < 64){
    float S = rs[c] + rs[c+64] + rs[c+128] + rs[c+192];
    float Q = rq[c] + rq[c+64] + rq[c+128] + rq[c+192];
    int batch = img >> 10;
    atomicAdd(&stats[batch*128 + c*2 + 0], S);
    atomicAdd(&stats[batch*128 + c*2 + 1], Q);
  }
}

// ---------- BN finalize ----------
__global__ void k_bnfin(const float* stats, float* ab, const void* g, const void* be,
                        int layer, float invc, const int* flag){
  __shared__ float gl[64], bel[64];
  int t = threadIdx.x;
  bool f32 = flag[0] != 0;
  if (t < 64){
    if (f32){ gl[t] = ((const float*)g)[t]; bel[t] = ((const float*)be)[t]; }
    else    { gl[t] = bf2f(((const uint16_t*)g)[t]); bel[t] = bf2f(((const uint16_t*)be)[t]); }
  }
  __syncthreads();
  if (t >= 128) return;
  int batch = t >> 6, c = t & 63;
  float s = stats[layer*256 + batch*128 + c*2];
  float q = stats[layer*256 + batch*128 + c*2 + 1];
  float mu = s*invc;
  float var = fmaxf(q*invc - mu*mu, 0.f);
  float A = gl[c] * rsqrtf(var + 1e-5f);
  float B = bel[c] - mu*A;
  ab[layer*256 + batch*128 + c*2]     = A;
  ab[layer*256 + batch*128 + c*2 + 1] = B;
}

// ---------- fused conv1+BN1+pool -> conv2 (weights chunked via overlay) ----------
__global__ __launch_bounds__(256) void k_conv2(const void* im0, const void* im1,
        const void* w1, const void* b1, const float* ab,
        const void* w2, const void* c2b, float* p2raw, float* stats, const int* flag){
  __shared__ float img[10816];    // 43264 B
  __shared__ float ovl[4608];     // 18432 B
  __shared__ float cbias[64];     //   total ~62 KB
  int b = blockIdx.x;
  int tid = threadIdx.x;
  bool f32 = flag[0] != 0;
  if (f32){
    const float* im = (b < 1024) ? ((const float*)im0 + b*784) : ((const float*)im1 + (b-1024)*784);
    for (int i = tid; i < 784; i += 256) ovl[i] = im[i];
    for (int i = tid; i < 576; i += 256) ovl[784+i] = ((const float*)w1)[i];
    if (tid < 64){ ovl[1360+tid] = ((const float*)b1)[tid]; cbias[tid] = ((const float*)c2b)[tid]; }
  } else {
    const uint16_t* im = (b < 1024) ? ((const uint16_t*)im0 + b*784) : ((const uint16_t*)im1 + (b-1024)*784);
    for (int i = tid; i < 784; i += 256) ovl[i] = bf2f(im[i]);
    for (int i = tid; i < 576; i += 256) ovl[784+i] = bf2f(((const uint16_t*)w1)[i]);
    if (tid < 64){ ovl[1360+tid] = bf2f(((const uint16_t*)b1)[tid]); cbias[tid] = bf2f(((const uint16_t*)c2b)[tid]); }
  }
  __syncthreads();
  int c = tid & 63, pg = tid >> 6;
  int batch = b >> 10;
  {
    float w[9];
    #pragma unroll
    for (int k = 0; k < 9; k++) w[k] = ovl[784 + c*9 + k];
    float bias = ovl[1360 + c];
    float A = ab[batch*128 + c*2], B = ab[batch*128 + c*2 + 1];
    for (int pp = pg; pp < 169; pp += 4){
      int py = pp/13, px = pp - py*13;
      float m = 0.f;    // ReLU folded into max
      #pragma unroll
      for (int q = 0; q < 4; q++){
        int yy = 2*py + (q>>1), xx = 2*px + (q&1);
        const float* p = ovl + yy*28 + xx;
        float acc = bias;
        #pragma unroll
        for (int dy = 0; dy < 3; dy++)
          #pragma unroll
          for (int dx = 0; dx < 3; dx++)
            acc += w[dy*3+dx]*p[dy*28+dx];
        m = fmaxf(m, A*acc + B);
      }
      img[c*169 + pp] = m;
    }
  }
  int lane = tid & 63, wv = tid >> 6;
  int pos0 = lane;
  int pos1 = lane + 64;
  bool v1 = (pos1 < 121);
  int p1c = v1 ? pos1 : pos0;
  int y0 = pos0/11, x0 = pos0 - y0*11;
  int y1 = p1c/11,  x1 = p1c - y1*11;
  float acc0[16], acc1[16];
  #pragma unroll
  for (int cc = 0; cc < 16; cc++){ acc0[cc]=0.f; acc1[cc]=0.f; }
  for (int ch = 0; ch < 8; ch++){
    int ci0 = ch*8;
    __syncthreads();
    if (f32){
      for (int i = tid; i < 4608; i += 256){
        int co = i/72, r = i - co*72;
        ovl[i] = ((const float*)w2)[(co*64 + ci0)*9 + r];
      }
    } else {
      for (int i = tid; i < 4608; i += 256){
        int co = i/72, r = i - co*72;
        ovl[i] = bf2f(((const uint16_t*)w2)[(co*64 + ci0)*9 + r]);
      }
    }
    __syncthreads();
    for (int cil = 0; cil < 8; cil++){
      int ci = ci0 + cil;
      float a[9], bv[9];
      const float* q0 = img + ci*169 + y0*13 + x0;
      const float* q1 = img + ci*169 + y1*13 + x1;
      #pragma unroll
      for (int dy = 0; dy < 3; dy++)
        #pragma unroll
        for (int dx = 0; dx < 3; dx++){
          a[dy*3+dx]  = q0[dy*13+dx];
          bv[dy*3+dx] = q1[dy*13+dx];
        }
      #pragma unroll
      for (int cc = 0; cc < 16; cc++){
        const float* wp = ovl + (wv*16+cc)*72 + cil*9;   // wave-uniform -> broadcast
        #pragma unroll
        for (int k = 0; k < 9; k++){
          acc0[cc] += wp[k]*a[k];
          acc1[cc] += wp[k]*bv[k];
        }
      }
    }
  }
  __syncthreads();                 // done reading img; reuse as raw-y2 buffer
  float* ybuf = img;
  #pragma unroll
  for (int cc = 0; cc < 16; cc++){
    int co = wv*16 + cc;
    float bs = cbias[co];
    float u0 = acc0[cc] + bs;
    float u1 = acc1[cc] + bs;
    ybuf[co*121 + pos0] = u0;
    if (v1) ybuf[co*121 + pos1] = u1;
    float s = u0 + (v1 ? u1 : 0.f);
    float q = u0*u0 + (v1 ? u1*u1 : 0.f);
    #pragma unroll
    for (int off = 32; off; off >>= 1){
      s += __shfl_down(s, off);
      q += __shfl_down(q, off);
    }
    if (lane == 0){
      atomicAdd(&stats[256 + batch*128 + co*2 + 0], s);
      atomicAdd(&stats[256 + batch*128 + co*2 + 1], q);
    }
  }
  __syncthreads();
  for (int idx = tid; idx < 1600; idx += 256){
    int cc = idx/25, pp = idx - cc*25;
    int py = pp/5, px = pp - py*5;
    const float* s = ybuf + cc*121;
    float m = fmaxf(fmaxf(s[(2*py)*11 + 2*px], s[(2*py)*11 + 2*px + 1]),
                    fmaxf(s[(2*py+1)*11 + 2*px], s[(2*py+1)*11 + 2*px + 1]));
    p2raw[(size_t)b*1600 + idx] = m;
  }
}

// ---------- conv3: BN2+ReLU staging, weights in 4-ci chunks; 8 images/block ----
__global__ __launch_bounds__(256) void k_conv3(const float* p2raw, const float* ab,
        const void* w3, const void* c3b, float* y3, float* stats, const int* flag){
  __shared__ float pimg[12800];    // 51200 B
  __shared__ float wch[2304];      // 9216 B
  __shared__ float cb3[64];
  __shared__ float abl[128];
  __shared__ float lstat[128];
  int b = blockIdx.x;
  int tid = threadIdx.x;
  bool f32 = flag[0] != 0;
  int batch = (b*8) >> 10;
  if (tid < 128){ abl[tid] = ab[256 + batch*128 + tid]; lstat[tid] = 0.f; }
  if (f32){ if (tid >= 128 && tid < 192) cb3[tid-128] = ((const float*)c3b)[tid-128]; }
  else    { if (tid >= 128 && tid < 192) cb3[tid-128] = bf2f(((const uint16_t*)c3b)[tid-128]); }
  __syncthreads();
  for (int idx = tid; idx < 12800; idx += 256){
    int rem = idx & 1599;
    int cch = rem / 25;
    pimg[idx] = fmaxf(abl[cch*2]*p2raw[(size_t)b*12800 + idx] + abl[cch*2+1], 0.f);
  }
  int il = tid >> 5, sub = tid & 31;
  float acc[18];
  #pragma unroll
  for (int s = 0; s < 18; s++){
    int o = sub + s*32;
    acc[s] = cb3[o/9];
  }
  for (int ch = 0; ch < 16; ch++){
    int ci0 = ch*4;
    __syncthreads();
    if (f32){
      for (int i = tid; i < 2304; i += 256){
        int co = i/36, r = i - co*36;
        wch[i] = ((const float*)w3)[(co*64 + ci0)*9 + r];
      }
    } else {
      for (int i = tid; i < 2304; i += 256){
        int co = i/36, r = i - co*36;
        wch[i] = bf2f(((const uint16_t*)w3)[(co*64 + ci0)*9 + r]);
      }
    }
    __syncthreads();
    #pragma unroll
    for (int s = 0; s < 18; s++){
      int o = sub + s*32;
      int co = o/9, pos = o - co*9;
      int y = pos/3, x = pos - y*3;
      float a = acc[s];
      #pragma unroll
      for (int cil = 0; cil < 4; cil++){
        const float* p = pimg + il*1600 + (ci0+cil)*25 + y*5 + x;
        const float* w = wch + co*36 + cil*9;
        #pragma unroll
        for (int dy = 0; dy < 3; dy++)
          #pragma unroll
          for (int dx = 0; dx < 3; dx++)
            a += w[dy*3+dx]*p[dy*5+dx];
      }
      acc[s] = a;
    }
  }
  #pragma unroll
  for (int s = 0; s < 18; s++){
    int o = sub + s*32;
    int co = o/9;
    y3[(size_t)(b*8+il)*576 + o] = acc[s];
    atomicAdd(&lstat[co*2 + 0], acc[s]);
    atomicAdd(&lstat[co*2 + 1], acc[s]*acc[s]);
  }
  __syncthreads();
  if (tid < 128)
    atomicAdd(&stats[512 + batch*128 + tid], lstat[tid]);
}

// ---------- BN3 + ReLU + pool (3->1) -> features ----------
__global__ __launch_bounds__(256) void k_pool3(const float* y3, const float* ab, float* ff){
  int idx = blockIdx.x*256 + threadIdx.x;   // 131072 exact
  int img = idx >> 6, c = idx & 63;
  int batch = img >> 10;
  float A = ab[512 + batch*128 + c*2], B = ab[512 + batch*128 + c*2 + 1];
  const float* p = y3 + (size_t)img*576 + c*9;
  float m = 0.f;
  m = fmaxf(m, A*p[0]+B);
  m = fmaxf(m, A*p[1]+B);
  m = fmaxf(m, A*p[3]+B);
  m = fmaxf(m, A*p[4]+B);
  ff[idx] = m;
}

// ---------- input projections ----------
__global__ __launch_bounds__(256) void k_xproj(const float* ff,
        const void* wi_f, const void* bi_f, const void* bh_f,
        const void* wi_b, const void* bi_b, const void* bh_b,
        const void* att_wih, const void* att_b,
        float* Xi, float* Xatt, const int* flag){
  int which = blockIdx.x >> 10, t = blockIdx.x & 1023;
  __shared__ float xv[64];
  bool f32 = flag[0] != 0;
  const float* row = (which == 0) ? ff + t*64
                   : (which == 1) ? ff + (1023 - t)*64
                   : ff + (1024 + t)*64;
  if (threadIdx.x < 64) xv[threadIdx.x] = row[threadIdx.x];
  __syncthreads();
  int j = threadIdx.x;
  if (which < 2){
    const void* wi = which ? wi_b : wi_f;
    const void* bi = which ? bi_b : bi_f;
    const void* bh = which ? bh_b : bh_f;
    float acc;
    if (f32){
      acc = ((const float*)bi)[j] + ((const float*)bh)[j];
      const float* wp = (const float*)wi + j*64;
      #pragma unroll 8
      for (int k = 0; k < 64; k++) acc += wp[k]*xv[k];
    } else {
      acc = bf2f(((const uint16_t*)bi)[j]) + bf2f(((const uint16_t*)bh)[j]);
      const uint16_t* wp = (const uint16_t*)wi + j*64;
      #pragma unroll 8
      for (int k = 0; k < 64; k++) acc += bf2f(wp[k])*xv[k];
    }
    Xi[(size_t)which*262144 + t*256 + j] = acc;
  } else {
    float acc;
    if (f32){
      acc = ((const float*)att_b)[j];
      for (int k = 0; k < 64; k++) acc += ((const float*)att_wih)[k*256 + j]*xv[k];
    } else {
      acc = bf2f(((const uint16_t*)att_b)[j]);
      for (int k = 0; k < 64; k++) acc += bf2f(((const uint16_t*)att_wih)[k*256 + j])*xv[k];
    }
    Xatt[t*256 + j] = acc;
  }
}

// ---------- BiLSTM scan: 2 blocks (fwd/bwd); float4 LDS h reads + X prefetch ---
__global__ __launch_bounds__(256, 1) void k_bilstm(const void* wh_f, const void* wh_b,
        const void* h0, const void* c0, const float* Xi, float* condA, float* condB,
        const int* flag){
  int dir = blockIdx.x;
  int j = threadIdx.x;
  bool f32 = flag[0] != 0;
  float w[64];
  if (f32){
    const float* wp = (const float*)(dir ? wh_b : wh_f) + j*64;
    #pragma unroll 8
    for (int k = 0; k < 64; k++) w[k] = wp[k];
  } else {
    const uint16_t* wp = (const uint16_t*)(dir ? wh_b : wh_f) + j*64;
    #pragma unroll 8
    for (int k = 0; k < 64; k++) w[k] = bf2f(wp[k]);
  }
  __shared__ __align__(16) float h[64];
  __shared__ float ga[256];
  float c = 0.f;
  if (j < 64){
    if (f32){ h[j] = ((const float*)h0)[dir*64 + j]; c = ((const float*)c0)[dir*64 + j]; }
    else    { h[j] = bf2f(((const uint16_t*)h0)[dir*64 + j]); c = bf2f(((const uint16_t*)c0)[dir*64 + j]); }
  }
  __syncthreads();
  const float* X = Xi + (size_t)dir*262144;
  float* out = dir ? condB : condA;
  float xcur = X[j];
  for (int t = 0; t < 1024; t++){
    float xnext = (t < 1023) ? X[(t+1)*256 + j] : 0.f;   // prefetch (hides L2 latency)
    float g0 = xcur, g1 = 0.f;
    #pragma unroll
    for (int k4 = 0; k4 < 16; k4 += 2){
      float4 ha = ((const float4*)h)[k4];
      float4 hb = ((const float4*)h)[k4+1];
      g0 += w[4*k4]*ha.x + w[4*k4+1]*ha.y + w[4*k4+2]*ha.z + w[4*k4+3]*ha.w;
      g1 += w[4*k4+4]*hb.x + w[4*k4+5]*hb.y + w[4*k4+6]*hb.z + w[4*k4+7]*hb.w;
    }
    float g = g0 + g1;
    // pytorch gate order i,f,g,o; wave-uniform activation select
    ga[j] = (j < 128 || j >= 192) ? fast_sig(g) : fast_tanh(g);
    __syncthreads();
    if (j < 64){
      c = ga[64+j]*c + ga[j]*ga[128+j];
      float hv = ga[192+j]*fast_tanh(c);
      h[j] = hv;
      out[t*64 + j] = hv;
    }
    xcur = xnext;
    __syncthreads();
  }
}

// ---------- cond_train = hf + hb_raw + ftr, row norms ----------
__global__ void k_cond(const float* condA, const float* condB, const float* ff,
                       float* cond, float* ncond){
  int t = blockIdx.x, j = threadIdx.x;   // 64 threads
  float v = condA[t*64+j] + condB[t*64+j] + ff[t*64+j];
  cond[t*64+j] = v;
  float s = v*v;
  #pragma unroll
  for (int off = 32; off; off >>= 1) s += __shfl_down(s, off);
  if (j == 0) ncond[t] = sqrtf(s);
}

// ---------- attention LSTM v3: 512 threads, cond register-resident -----------
// __launch_bounds__(512, 2): 8 waves/CU = 2 waves/SIMD -> 256-VGPR budget so
// wk[64]+row0[64]+row1[64] (~222 VGPRs) stay in registers (R6's (512) default
// capped at 92 VGPRs and spilled rows to scratch -> 7.3ms).
__global__ __launch_bounds__(512, 2) void k_attlstm(
        const float* cond, const float* Xatt, const float* ff,
        const void* whh, const void* ah0, const void* ac0, const void* ar0,
        float* ctest, const int* flag){
  __shared__ float hr[128];            // h | r
  __shared__ float gpart[512];
  __shared__ float pbuf[512*17];       // 34816 B
  __shared__ float rs2[4][32*17];      // 8704 B
  __shared__ float wred[16];           // [0..7] max, [8..15] sum
  int tid = threadIdx.x;
  bool f32 = flag[0] != 0;
  int j = tid & 255, half = tid >> 8;
  float wk[64];
  if (f32){
    const float* W = (const float*)whh;
    #pragma unroll 8
    for (int k = 0; k < 64; k++) wk[k] = W[(half*64+k)*256 + j];
  } else {
    const uint16_t* W = (const uint16_t*)whh;
    #pragma unroll 8
    for (int k = 0; k < 64; k++) wk[k] = bf2f(W[(half*64+k)*256 + j]);
  }
  float row0[64], row1[64];
  {
    const float4* r0 = (const float4*)(cond + (size_t)tid*64);
    const float4* r1 = (const float4*)(cond + (size_t)(tid+512)*64);
    #pragma unroll
    for (int k4 = 0; k4 < 16; k4++){
      float4 a = r0[k4]; float4 b = r1[k4];
      row0[4*k4]=a.x; row0[4*k4+1]=a.y; row0[4*k4+2]=a.z; row0[4*k4+3]=a.w;
      row1[4*k4]=b.x; row1[4*k4+1]=b.y; row1[4*k4+2]=b.z; row1[4*k4+3]=b.w;
    }
  }
  float c = 0.f;
  if (f32){
    if (tid < 64){ hr[tid] = ((const float*)ah0)[tid]; c = ((const float*)ac0)[tid]; }
    else if (tid < 128) hr[tid] = ((const float*)ar0)[tid-64];
  } else {
    if (tid < 64){ hr[tid] = bf2f(((const uint16_t*)ah0)[tid]); c = bf2f(((const uint16_t*)ac0)[tid]); }
    else if (tid < 128) hr[tid] = bf2f(((const uint16_t*)ar0)[tid-64]);
  }
  __syncthreads();
  int lane = tid & 63, wv = tid >> 6;
  const float* fte = ff + 65536;
  for (int st = 0; st < 1024; st++){
    // ---- phase 1: gate half-dots (all 512); 2 accumulators break dep chain ----
    float ga0 = (half == 0) ? Xatt[st*256 + j] : 0.f, ga1 = 0.f;
    {
      const float4* hc = (const float4*)(hr + half*64);
      #pragma unroll
      for (int k4 = 0; k4 < 16; k4 += 2){
        float4 hv = hc[k4];
        float4 hw = hc[k4+1];
        ga0 += wk[4*k4]*hv.x + wk[4*k4+1]*hv.y + wk[4*k4+2]*hv.z + wk[4*k4+3]*hv.w;
        ga1 += wk[4*k4+4]*hw.x + wk[4*k4+5]*hw.y + wk[4*k4+6]*hw.z + wk[4*k4+7]*hw.w;
      }
    }
    gpart[tid] = ga0 + ga1;
    __syncthreads();                                   // B1
    // ---- phase 2: wave 0 computes gates (order f,i,o,g) + cell ----
    if (tid < 64){
      float xres = fte[st*64 + tid];
      float gf = gpart[tid]     + gpart[256+tid];
      float gi = gpart[64+tid]  + gpart[320+tid];
      float go = gpart[128+tid] + gpart[384+tid];
      float gg = gpart[192+tid] + gpart[448+tid];
      float f_ = fast_sig(gf), i_ = fast_sig(gi), o_ = fast_sig(go), g_ = fast_tanh(gg);
      c = f_*c + i_*g_;
      float hv = o_*fast_tanh(c) + xres;
      hr[tid] = hv;
      ctest[st*64 + tid] = hv;
    }
    __syncthreads();                                   // B2
    // ---- QK from register rows (zero memory traffic for cond) ----
    float lg0a = 0.f, lg0b = 0.f, lg1a = 0.f, lg1b = 0.f;
    {
      const float4* hq = (const float4*)hr;
      #pragma unroll
      for (int k4 = 0; k4 < 16; k4 += 2){
        float4 hv = hq[k4];
        float4 hw = hq[k4+1];
        lg0a += row0[4*k4]*hv.x + row0[4*k4+1]*hv.y + row0[4*k4+2]*hv.z + row0[4*k4+3]*hv.w;
        lg0b += row0[4*k4+4]*hw.x + row0[4*k4+5]*hw.y + row0[4*k4+6]*hw.z + row0[4*k4+7]*hw.w;
        lg1a += row1[4*k4]*hv.x + row1[4*k4+1]*hv.y + row1[4*k4+2]*hv.z + row1[4*k4+3]*hv.w;
        lg1b += row1[4*k4+4]*hw.x + row1[4*k4+5]*hw.y + row1[4*k4+6]*hw.z + row1[4*k4+7]*hw.w;
      }
    }
    float lg0 = lg0a + lg0b, lg1 = lg1a + lg1b;
    // ---- softmax max ----
    float mx = fmaxf(lg0, lg1);
    #pragma unroll
    for (int off = 32; off; off >>= 1) mx = fmaxf(mx, __shfl_xor(mx, off));
    if (lane == 0) wred[wv] = mx;
    __syncthreads();                                   // B3
    float gmax = fmaxf(fmaxf(fmaxf(wred[0],wred[1]),fmaxf(wred[2],wred[3])),
                       fmaxf(fmaxf(wred[4],wred[5]),fmaxf(wred[6],wred[7])));
    float e0 = __expf(lg0 - gmax), e1 = __expf(lg1 - gmax);
    float s = e0 + e1;
    #pragma unroll
    for (int off = 32; off; off >>= 1) s += __shfl_xor(s, off);
    if (lane == 0) wred[8+wv] = s;
    __syncthreads();                                   // B4
    float inv = 1.f/(((wred[8]+wred[9])+(wred[10]+wred[11]))
                   + ((wred[12]+wred[13])+(wred[14]+wred[15])));
    // ---- AV: 4 chunks x 16 columns, exact fp32 LDS partial reduction ----
    #pragma unroll
    for (int ch = 0; ch < 4; ch++){
      #pragma unroll
      for (int k = 0; k < 16; k++)
        pbuf[tid*17 + k] = e0*row0[ch*16+k] + e1*row1[ch*16+k];
      __syncthreads();                                 // Bav-w
      {
        int kk = tid & 15, seg = tid >> 4;             // 32 segs x 16 rows
        float a = 0.f;
        #pragma unroll
        for (int q = 0; q < 16; q++)
          a += pbuf[(seg*16+q)*17 + kk];
        rs2[ch][seg*17 + kk] = a;
      }
      __syncthreads();                                 // Bav-r (pbuf reuse safe)
    }
    // ---- final r assembly by wave 0 ----
    if (tid < 64){
      int kk = lane & 15, chq = lane >> 4;             // column = chq*16+kk = lane
      float a = 0.f;
      #pragma unroll
      for (int sgm = 0; sgm < 32; sgm++) a += rs2[chq][sgm*17 + kk];
      hr[64 + lane] = a * inv;
    }
    __syncthreads();                                   // B-loop
  }
}

// ---------- final cosine-softmax label readout (output dtype follows sniff) ----
__global__ __launch_bounds__(256) void k_final(const float* ctest, const float* cond,
        const float* ncond, const void* labels, void* out, const int* flag){
  int t = blockIdx.x;
  __shared__ __align__(16) float q[64];
  __shared__ float sim[1024];
  __shared__ float red[4];
  __shared__ float accw[20];
  __shared__ float bcv[2];
  int tid = threadIdx.x;
  bool f32 = flag[0] != 0;
  if (tid < 64) q[tid] = ctest[t*64 + tid];
  if (tid < 20) accw[tid] = 0.f;
  __syncthreads();
  if (tid < 64){
    float s = q[tid]*q[tid];
    #pragma unroll
    for (int off = 32; off; off >>= 1) s += __shfl_down(s, off);
    if (tid == 0) bcv[0] = sqrtf(s);
  }
  __syncthreads();
  float nq = bcv[0];
  float mymax = -1e30f;
  for (int i = tid; i < 1024; i += 256){
    float d = 0.f;
    const float4* cr = (const float4*)(cond + i*64);
    #pragma unroll
    for (int k4 = 0; k4 < 16; k4++){
      float4 cv = cr[k4];
      float4 qv = ((const float4*)q)[k4];
      d += cv.x*qv.x + cv.y*qv.y + cv.z*qv.z + cv.w*qv.w;
    }
    float den = fmaxf(nq*ncond[i], 1e-8f);
    float sv = d/den;
    sim[i] = sv;
    mymax = fmaxf(mymax, sv);
  }
  int lane = tid & 63, wv = tid >> 6;
  #pragma unroll
  for (int off = 32; off; off >>= 1) mymax = fmaxf(mymax, __shfl_down(mymax, off));
  if (lane == 0) red[wv] = mymax;
  __syncthreads();
  if (tid == 0) bcv[1] = fmaxf(fmaxf(red[0], red[1]), fmaxf(red[2], red[3]));
  __syncthreads();
  float smax = bcv[1];
  float es = 0.f;
  float la[20];
  #pragma unroll
  for (int w = 0; w < 20; w++) la[w] = 0.f;
  if (f32){
    for (int i = tid; i < 1024; i += 256){
      float e = __expf(sim[i] - smax);
      es += e;
      const float* L = (const float*)labels + i*20;
      #pragma unroll
      for (int w = 0; w < 20; w++) la[w] += e*L[w];
    }
  } else {
    for (int i = tid; i < 1024; i += 256){
      float e = __expf(sim[i] - smax);
      es += e;
      const uint16_t* L = (const uint16_t*)labels + i*20;
      #pragma unroll
      for (int w = 0; w < 20; w++) la[w] += e*bf2f(L[w]);
    }
  }
  #pragma unroll
  for (int off = 32; off; off >>= 1) es += __shfl_down(es, off);
  if (lane == 0) red[wv] = es;
  #pragma unroll
  for (int w = 0; w < 20; w++) atomicAdd(&accw[w], la[w]);
  __syncthreads();
  if (tid == 0) bcv[0] = 1.f/(red[0] + red[1] + red[2] + red[3]);
  __syncthreads();
  if (tid < 20){
    float v = accw[tid]*bcv[0];
    if (f32) ((float*)out)[t*20 + tid] = v;
    else     ((uint16_t*)out)[t*20 + tid] = f2bf(v);
  }
}

// ---------- host launcher ----------
extern "C" void kernel_launch(void* const* d_in, const int* in_sizes, int n_in,
                              void* d_out, int out_size, void* d_ws, size_t ws_size,
                              hipStream_t stream){
  const void* trainIm    = d_in[0];
  const void* trainLabel = d_in[1];
  const void* testIm     = d_in[2];
  const void* c1w  = d_in[4];
  const void* c1b  = d_in[5];
  const void* bn1g = d_in[6];
  const void* bn1b = d_in[7];
  const void* c2w  = d_in[8];
  const void* c2b  = d_in[9];
  const void* bn2g = d_in[10];
  const void* bn2b = d_in[11];
  const void* c3w  = d_in[12];
  const void* c3b  = d_in[13];
  const void* bn3g = d_in[14];
  const void* bn3b = d_in[15];
  const void* wi_f = d_in[16];
  const void* wh_f = d_in[17];
  const void* bi_f = d_in[18];
  const void* bh_f = d_in[19];
  const void* wi_b = d_in[20];
  const void* wh_b = d_in[21];
  const void* bi_b = d_in[22];
  const void* bh_b = d_in[23];
  const void* h0   = d_in[24];
  const void* c0   = d_in[25];
  const void* att_wih = d_in[26];
  const void* att_whh = d_in[27];
  const void* att_b   = d_in[28];
  const void* att_h0  = d_in[29];
  const void* att_c0  = d_in[30];
  const void* att_r0  = d_in[31];

  char* ws = (char*)d_ws;
  float* stats = (float*)(ws + OFF_STATS);
  int*   flag  = (int*)(ws + OFF_FLAG);
  float* ab    = (float*)(ws + OFF_AB);
  float* p2raw = (float*)(ws + OFF_P2R);
  float* y3    = (float*)(ws + OFF_Y3);
  float* ff    = (float*)(ws + OFF_F);
  float* Xi    = (float*)(ws + OFF_XI);
  float* Xatt  = (float*)(ws + OFF_XATT);
  float* condA = (float*)(ws + OFF_CA);
  float* condB = (float*)(ws + OFF_CB);
  float* cond  = (float*)(ws + OFF_COND);
  float* ncond = (float*)(ws + OFF_NC);
  float* ctest = (float*)(ws + OFF_CT);

  k_sniff<<<1, 256, 0, stream>>>((const uint32_t*)trainIm, stats, flag);
  k_conv1_stats<<<2048, 256, 0, stream>>>(trainIm, testIm, c1w, c1b, stats, flag);
  k_bnfin<<<1, 192, 0, stream>>>(stats, ab, bn1g, bn1b, 0, 1.f/692224.f, flag);
  k_conv2<<<2048, 256, 0, stream>>>(trainIm, testIm, c1w, c1b, ab, c2w, c2b, p2raw, stats, flag);
  k_bnfin<<<1, 192, 0, stream>>>(stats, ab, bn2g, bn2b, 1, 1.f/123904.f, flag);
  k_conv3<<<256, 256, 0, stream>>>(p2raw, ab, c3w, c3b, y3, stats, flag);
  k_bnfin<<<1, 192, 0, stream>>>(stats, ab, bn3g, bn3b, 2, 1.f/9216.f, flag);
  k_pool3<<<512, 256, 0, stream>>>(y3, ab, ff);
  k_xproj<<<3072, 256, 0, stream>>>(ff, wi_f, bi_f, bh_f, wi_b, bi_b, bh_b, att_wih, att_b, Xi, Xatt, flag);
  k_bilstm<<<2, 256, 0, stream>>>(wh_f, wh_b, h0, c0, Xi, condA, condB, flag);
  k_cond<<<1024, 64, 0, stream>>>(condA, condB, ff, cond, ncond);
  k_attlstm<<<1, 512, 0, stream>>>(cond, Xatt, ff, att_whh, att_h0, att_c0, att_r0, ctest, flag);
  k_final<<<1024, 256, 0, stream>>>(ctest, cond, ncond, trainLabel, d_out, flag);
}

// Round 8
// 5985.526 us; speedup vs baseline: 1.8629x; 1.8629x over previous
//
#include <hip/hip_runtime.h>
#include <stdint.h>

// ---------- helpers ----------
__device__ __forceinline__ float bf2f(uint16_t v){ return __uint_as_float(((uint32_t)v) << 16); }
__device__ __forceinline__ uint16_t f2bf(float x){
  uint32_t u = __float_as_uint(x);
  return (uint16_t)((u + 0x7fffu + ((u >> 16) & 1u)) >> 16);
}
__device__ __forceinline__ float sigf(float x){
  float cx = fminf(fmaxf(x, -88.f), 88.f);     // exact for |x|<88; scrubs NaN
  return 1.f/(1.f + expf(-cx));
}
__device__ __forceinline__ float tanh_s(float x){
  float cx = fminf(fmaxf(x, -44.f), 44.f);
  return tanhf(cx);
}
// fast variants for the hot recurrent kernels (v_exp_f32-based, ~1e-7 rel err)
__device__ __forceinline__ float fast_sig(float x){
  float cx = fminf(fmaxf(x, -60.f), 60.f);
  return 1.f/(1.f + __expf(-cx));
}
__device__ __forceinline__ float fast_tanh(float x){
  float cx = fminf(fmaxf(x, -15.f), 15.f);
  float e = __expf(2.f*cx);
  return (e - 1.f)/(e + 1.f);
}

// ---------- workspace layout (bytes) — total ~22.6 MB ----------
static const size_t OFF_STATS = 0;            // 768 fp32
static const size_t OFF_FLAG  = 3072;         // 1 int (1 = fp32 inputs, 0 = bf16)
static const size_t OFF_AB    = 4096;         // 768 fp32
static const size_t OFF_P2R   = 8192;         // 2048*64*25 fp32 = 13107200
static const size_t OFF_Y3    = 13115392;     // 2048*576 fp32 = 4718592
static const size_t OFF_F     = 17833984;     // 2048*64 fp32
static const size_t OFF_XI    = 18358272;     // 2*1024*256 fp32
static const size_t OFF_XATT  = 20455424;     // 1024*256 fp32
static const size_t OFF_CA    = 21504000;
static const size_t OFF_CB    = 21766144;
static const size_t OFF_COND  = 22028288;
static const size_t OFF_NC    = 22290432;
static const size_t OFF_CT    = 22294528;     // ends 22556672

// ---------- sniff input dtype + zero stats ----------
__global__ void k_sniff(const uint32_t* im, float* stats, int* flag){
  int t = threadIdx.x;
  for (int i = t; i < 768; i += 256) stats[i] = 0.f;
  if (t < 64){
    uint32_t w = im[t];
    uint32_t e = (w >> 7) & 0xffu;             // exponent of low-half-as-bf16
    bool sane = (e >= 100u && e <= 140u);      // N(0,1) bf16 exponents land here
    unsigned long long m = __ballot(sane);
    if (t == 0) flag[0] = (__popcll(m) < 48) ? 1 : 0;   // junk exponents => fp32 data
  }
}

// ---------- conv1 stats ----------
__global__ __launch_bounds__(256) void k_conv1_stats(const void* im0, const void* im1,
        const void* w1, const void* b1, float* stats, const int* flag){
  __shared__ float xs[784];
  __shared__ float wl[576];
  __shared__ float bl1[64];
  __shared__ float rs[256], rq[256];
  int img = blockIdx.x;
  bool f32 = flag[0] != 0;
  if (f32){
    const float* im = (img < 1024) ? ((const float*)im0 + img*784) : ((const float*)im1 + (img-1024)*784);
    for (int i = threadIdx.x; i < 784; i += 256) xs[i] = im[i];
    for (int i = threadIdx.x; i < 576; i += 256) wl[i] = ((const float*)w1)[i];
    if (threadIdx.x < 64) bl1[threadIdx.x] = ((const float*)b1)[threadIdx.x];
  } else {
    const uint16_t* im = (img < 1024) ? ((const uint16_t*)im0 + img*784) : ((const uint16_t*)im1 + (img-1024)*784);
    for (int i = threadIdx.x; i < 784; i += 256) xs[i] = bf2f(im[i]);
    for (int i = threadIdx.x; i < 576; i += 256) wl[i] = bf2f(((const uint16_t*)w1)[i]);
    if (threadIdx.x < 64) bl1[threadIdx.x] = bf2f(((const uint16_t*)b1)[threadIdx.x]);
  }
  __syncthreads();
  int c = threadIdx.x & 63, pg = threadIdx.x >> 6;
  float w[9];
  #pragma unroll
  for (int k = 0; k < 9; k++) w[k] = wl[c*9+k];
  float bias = bl1[c];
  float s = 0.f, q = 0.f;
  for (int pos = pg; pos < 676; pos += 4){
    int y = pos/26, x = pos - y*26;
    const float* p = xs + y*28 + x;
    float acc = bias;
    #pragma unroll
    for (int dy = 0; dy < 3; dy++)
      #pragma unroll
      for (int dx = 0; dx < 3; dx++)
        acc += w[dy*3+dx]*p[dy*28+dx];
    s += acc; q += acc*acc;
  }
  rs[threadIdx.x] = s; rq[threadIdx.x] = q;
  __syncthreads();
  if (threadIdx.x < 64){
    float S = rs[c] + rs[c+64] + rs[c+128] + rs[c+192];
    float Q = rq[c] + rq[c+64] + rq[c+128] + rq[c+192];
    int batch = img >> 10;
    atomicAdd(&stats[batch*128 + c*2 + 0], S);
    atomicAdd(&stats[batch*128 + c*2 + 1], Q);
  }
}

// ---------- BN finalize ----------
__global__ void k_bnfin(const float* stats, float* ab, const void* g, const void* be,
                        int layer, float invc, const int* flag){
  __shared__ float gl[64], bel[64];
  int t = threadIdx.x;
  bool f32 = flag[0] != 0;
  if (t < 64){
    if (f32){ gl[t] = ((const float*)g)[t]; bel[t] = ((const float*)be)[t]; }
    else    { gl[t] = bf2f(((const uint16_t*)g)[t]); bel[t] = bf2f(((const uint16_t*)be)[t]); }
  }
  __syncthreads();
  if (t >= 128) return;
  int batch = t >> 6, c = t & 63;
  float s = stats[layer*256 + batch*128 + c*2];
  float q = stats[layer*256 + batch*128 + c*2 + 1];
  float mu = s*invc;
  float var = fmaxf(q*invc - mu*mu, 0.f);
  float A = gl[c] * rsqrtf(var + 1e-5f);
  float B = bel[c] - mu*A;
  ab[layer*256 + batch*128 + c*2]     = A;
  ab[layer*256 + batch*128 + c*2 + 1] = B;
}

// ---------- fused conv1+BN1+pool -> conv2 (weights chunked via overlay) ----------
__global__ __launch_bounds__(256) void k_conv2(const void* im0, const void* im1,
        const void* w1, const void* b1, const float* ab,
        const void* w2, const void* c2b, float* p2raw, float* stats, const int* flag){
  __shared__ float img[10816];    // 43264 B
  __shared__ float ovl[4608];     // 18432 B
  __shared__ float cbias[64];     //   total ~62 KB
  int b = blockIdx.x;
  int tid = threadIdx.x;
  bool f32 = flag[0] != 0;
  if (f32){
    const float* im = (b < 1024) ? ((const float*)im0 + b*784) : ((const float*)im1 + (b-1024)*784);
    for (int i = tid; i < 784; i += 256) ovl[i] = im[i];
    for (int i = tid; i < 576; i += 256) ovl[784+i] = ((const float*)w1)[i];
    if (tid < 64){ ovl[1360+tid] = ((const float*)b1)[tid]; cbias[tid] = ((const float*)c2b)[tid]; }
  } else {
    const uint16_t* im = (b < 1024) ? ((const uint16_t*)im0 + b*784) : ((const uint16_t*)im1 + (b-1024)*784);
    for (int i = tid; i < 784; i += 256) ovl[i] = bf2f(im[i]);
    for (int i = tid; i < 576; i += 256) ovl[784+i] = bf2f(((const uint16_t*)w1)[i]);
    if (tid < 64){ ovl[1360+tid] = bf2f(((const uint16_t*)b1)[tid]); cbias[tid] = bf2f(((const uint16_t*)c2b)[tid]); }
  }
  __syncthreads();
  int c = tid & 63, pg = tid >> 6;
  int batch = b >> 10;
  {
    float w[9];
    #pragma unroll
    for (int k = 0; k < 9; k++) w[k] = ovl[784 + c*9 + k];
    float bias = ovl[1360 + c];
    float A = ab[batch*128 + c*2], B = ab[batch*128 + c*2 + 1];
    for (int pp = pg; pp < 169; pp += 4){
      int py = pp/13, px = pp - py*13;
      float m = 0.f;    // ReLU folded into max
      #pragma unroll
      for (int q = 0; q < 4; q++){
        int yy = 2*py + (q>>1), xx = 2*px + (q&1);
        const float* p = ovl + yy*28 + xx;
        float acc = bias;
        #pragma unroll
        for (int dy = 0; dy < 3; dy++)
          #pragma unroll
          for (int dx = 0; dx < 3; dx++)
            acc += w[dy*3+dx]*p[dy*28+dx];
        m = fmaxf(m, A*acc + B);
      }
      img[c*169 + pp] = m;
    }
  }
  int lane = tid & 63, wv = tid >> 6;
  int pos0 = lane;
  int pos1 = lane + 64;
  bool v1 = (pos1 < 121);
  int p1c = v1 ? pos1 : pos0;
  int y0 = pos0/11, x0 = pos0 - y0*11;
  int y1 = p1c/11,  x1 = p1c - y1*11;
  float acc0[16], acc1[16];
  #pragma unroll
  for (int cc = 0; cc < 16; cc++){ acc0[cc]=0.f; acc1[cc]=0.f; }
  for (int ch = 0; ch < 8; ch++){
    int ci0 = ch*8;
    __syncthreads();
    if (f32){
      for (int i = tid; i < 4608; i += 256){
        int co = i/72, r = i - co*72;
        ovl[i] = ((const float*)w2)[(co*64 + ci0)*9 + r];
      }
    } else {
      for (int i = tid; i < 4608; i += 256){
        int co = i/72, r = i - co*72;
        ovl[i] = bf2f(((const uint16_t*)w2)[(co*64 + ci0)*9 + r]);
      }
    }
    __syncthreads();
    for (int cil = 0; cil < 8; cil++){
      int ci = ci0 + cil;
      float a[9], bv[9];
      const float* q0 = img + ci*169 + y0*13 + x0;
      const float* q1 = img + ci*169 + y1*13 + x1;
      #pragma unroll
      for (int dy = 0; dy < 3; dy++)
        #pragma unroll
        for (int dx = 0; dx < 3; dx++){
          a[dy*3+dx]  = q0[dy*13+dx];
          bv[dy*3+dx] = q1[dy*13+dx];
        }
      #pragma unroll
      for (int cc = 0; cc < 16; cc++){
        const float* wp = ovl + (wv*16+cc)*72 + cil*9;   // wave-uniform -> broadcast
        #pragma unroll
        for (int k = 0; k < 9; k++){
          acc0[cc] += wp[k]*a[k];
          acc1[cc] += wp[k]*bv[k];
        }
      }
    }
  }
  __syncthreads();                 // done reading img; reuse as raw-y2 buffer
  float* ybuf = img;
  #pragma unroll
  for (int cc = 0; cc < 16; cc++){
    int co = wv*16 + cc;
    float bs = cbias[co];
    float u0 = acc0[cc] + bs;
    float u1 = acc1[cc] + bs;
    ybuf[co*121 + pos0] = u0;
    if (v1) ybuf[co*121 + pos1] = u1;
    float s = u0 + (v1 ? u1 : 0.f);
    float q = u0*u0 + (v1 ? u1*u1 : 0.f);
    #pragma unroll
    for (int off = 32; off; off >>= 1){
      s += __shfl_down(s, off);
      q += __shfl_down(q, off);
    }
    if (lane == 0){
      atomicAdd(&stats[256 + batch*128 + co*2 + 0], s);
      atomicAdd(&stats[256 + batch*128 + co*2 + 1], q);
    }
  }
  __syncthreads();
  for (int idx = tid; idx < 1600; idx += 256){
    int cc = idx/25, pp = idx - cc*25;
    int py = pp/5, px = pp - py*5;
    const float* s = ybuf + cc*121;
    float m = fmaxf(fmaxf(s[(2*py)*11 + 2*px], s[(2*py)*11 + 2*px + 1]),
                    fmaxf(s[(2*py+1)*11 + 2*px], s[(2*py+1)*11 + 2*px + 1]));
    p2raw[(size_t)b*1600 + idx] = m;
  }
}

// ---------- conv3: BN2+ReLU staging, weights in 4-ci chunks; 8 images/block ----
__global__ __launch_bounds__(256) void k_conv3(const float* p2raw, const float* ab,
        const void* w3, const void* c3b, float* y3, float* stats, const int* flag){
  __shared__ float pimg[12800];    // 51200 B
  __shared__ float wch[2304];      // 9216 B
  __shared__ float cb3[64];
  __shared__ float abl[128];
  __shared__ float lstat[128];
  int b = blockIdx.x;
  int tid = threadIdx.x;
  bool f32 = flag[0] != 0;
  int batch = (b*8) >> 10;
  if (tid < 128){ abl[tid] = ab[256 + batch*128 + tid]; lstat[tid] = 0.f; }
  if (f32){ if (tid >= 128 && tid < 192) cb3[tid-128] = ((const float*)c3b)[tid-128]; }
  else    { if (tid >= 128 && tid < 192) cb3[tid-128] = bf2f(((const uint16_t*)c3b)[tid-128]); }
  __syncthreads();
  for (int idx = tid; idx < 12800; idx += 256){
    int rem = idx & 1599;
    int cch = rem / 25;
    pimg[idx] = fmaxf(abl[cch*2]*p2raw[(size_t)b*12800 + idx] + abl[cch*2+1], 0.f);
  }
  int il = tid >> 5, sub = tid & 31;
  float acc[18];
  #pragma unroll
  for (int s = 0; s < 18; s++){
    int o = sub + s*32;
    acc[s] = cb3[o/9];
  }
  for (int ch = 0; ch < 16; ch++){
    int ci0 = ch*4;
    __syncthreads();
    if (f32){
      for (int i = tid; i < 2304; i += 256){
        int co = i/36, r = i - co*36;
        wch[i] = ((const float*)w3)[(co*64 + ci0)*9 + r];
      }
    } else {
      for (int i = tid; i < 2304; i += 256){
        int co = i/36, r = i - co*36;
        wch[i] = bf2f(((const uint16_t*)w3)[(co*64 + ci0)*9 + r]);
      }
    }
    __syncthreads();
    #pragma unroll
    for (int s = 0; s < 18; s++){
      int o = sub + s*32;
      int co = o/9, pos = o - co*9;
      int y = pos/3, x = pos - y*3;
      float a = acc[s];
      #pragma unroll
      for (int cil = 0; cil < 4; cil++){
        const float* p = pimg + il*1600 + (ci0+cil)*25 + y*5 + x;
        const float* w = wch + co*36 + cil*9;
        #pragma unroll
        for (int dy = 0; dy < 3; dy++)
          #pragma unroll
          for (int dx = 0; dx < 3; dx++)
            a += w[dy*3+dx]*p[dy*5+dx];
      }
      acc[s] = a;
    }
  }
  #pragma unroll
  for (int s = 0; s < 18; s++){
    int o = sub + s*32;
    int co = o/9;
    y3[(size_t)(b*8+il)*576 + o] = acc[s];
    atomicAdd(&lstat[co*2 + 0], acc[s]);
    atomicAdd(&lstat[co*2 + 1], acc[s]*acc[s]);
  }
  __syncthreads();
  if (tid < 128)
    atomicAdd(&stats[512 + batch*128 + tid], lstat[tid]);
}

// ---------- BN3 + ReLU + pool (3->1) -> features ----------
__global__ __launch_bounds__(256) void k_pool3(const float* y3, const float* ab, float* ff){
  int idx = blockIdx.x*256 + threadIdx.x;   // 131072 exact
  int img = idx >> 6, c = idx & 63;
  int batch = img >> 10;
  float A = ab[512 + batch*128 + c*2], B = ab[512 + batch*128 + c*2 + 1];
  const float* p = y3 + (size_t)img*576 + c*9;
  float m = 0.f;
  m = fmaxf(m, A*p[0]+B);
  m = fmaxf(m, A*p[1]+B);
  m = fmaxf(m, A*p[3]+B);
  m = fmaxf(m, A*p[4]+B);
  ff[idx] = m;
}

// ---------- input projections ----------
__global__ __launch_bounds__(256) void k_xproj(const float* ff,
        const void* wi_f, const void* bi_f, const void* bh_f,
        const void* wi_b, const void* bi_b, const void* bh_b,
        const void* att_wih, const void* att_b,
        float* Xi, float* Xatt, const int* flag){
  int which = blockIdx.x >> 10, t = blockIdx.x & 1023;
  __shared__ float xv[64];
  bool f32 = flag[0] != 0;
  const float* row = (which == 0) ? ff + t*64
                   : (which == 1) ? ff + (1023 - t)*64
                   : ff + (1024 + t)*64;
  if (threadIdx.x < 64) xv[threadIdx.x] = row[threadIdx.x];
  __syncthreads();
  int j = threadIdx.x;
  if (which < 2){
    const void* wi = which ? wi_b : wi_f;
    const void* bi = which ? bi_b : bi_f;
    const void* bh = which ? bh_b : bh_f;
    float acc;
    if (f32){
      acc = ((const float*)bi)[j] + ((const float*)bh)[j];
      const float* wp = (const float*)wi + j*64;
      #pragma unroll 8
      for (int k = 0; k < 64; k++) acc += wp[k]*xv[k];
    } else {
      acc = bf2f(((const uint16_t*)bi)[j]) + bf2f(((const uint16_t*)bh)[j]);
      const uint16_t* wp = (const uint16_t*)wi + j*64;
      #pragma unroll 8
      for (int k = 0; k < 64; k++) acc += bf2f(wp[k])*xv[k];
    }
    Xi[(size_t)which*262144 + t*256 + j] = acc;
  } else {
    float acc;
    if (f32){
      acc = ((const float*)att_b)[j];
      for (int k = 0; k < 64; k++) acc += ((const float*)att_wih)[k*256 + j]*xv[k];
    } else {
      acc = bf2f(((const uint16_t*)att_b)[j]);
      for (int k = 0; k < 64; k++) acc += bf2f(((const uint16_t*)att_wih)[k*256 + j])*xv[k];
    }
    Xatt[t*256 + j] = acc;
  }
}

// ---------- BiLSTM scan: 2 blocks (fwd/bwd); FULLY-unrolled weight load so
// w[64] is SROA-promoted to VGPRs (partial unroll left it in scratch) ---------
__global__ __launch_bounds__(256, 1) void k_bilstm(const void* wh_f, const void* wh_b,
        const void* h0, const void* c0, const float* Xi, float* condA, float* condB,
        const int* flag){
  int dir = blockIdx.x;
  int j = threadIdx.x;
  bool f32 = flag[0] != 0;
  float w[64];
  if (f32){
    const float* wp = (const float*)(dir ? wh_b : wh_f) + j*64;
    #pragma unroll
    for (int k = 0; k < 64; k++) w[k] = wp[k];
  } else {
    const uint16_t* wp = (const uint16_t*)(dir ? wh_b : wh_f) + j*64;
    #pragma unroll
    for (int k = 0; k < 64; k++) w[k] = bf2f(wp[k]);
  }
  __shared__ __align__(16) float h[64];
  __shared__ float ga[256];
  float c = 0.f;
  if (j < 64){
    if (f32){ h[j] = ((const float*)h0)[dir*64 + j]; c = ((const float*)c0)[dir*64 + j]; }
    else    { h[j] = bf2f(((const uint16_t*)h0)[dir*64 + j]); c = bf2f(((const uint16_t*)c0)[dir*64 + j]); }
  }
  __syncthreads();
  const float* X = Xi + (size_t)dir*262144;
  float* out = dir ? condB : condA;
  float xcur = X[j];
  for (int t = 0; t < 1024; t++){
    float xnext = (t < 1023) ? X[(t+1)*256 + j] : 0.f;   // prefetch (hides L2 latency)
    float g0 = xcur, g1 = 0.f;
    #pragma unroll
    for (int k4 = 0; k4 < 16; k4 += 2){
      float4 ha = ((const float4*)h)[k4];
      float4 hb = ((const float4*)h)[k4+1];
      g0 += w[4*k4]*ha.x + w[4*k4+1]*ha.y + w[4*k4+2]*ha.z + w[4*k4+3]*ha.w;
      g1 += w[4*k4+4]*hb.x + w[4*k4+5]*hb.y + w[4*k4+6]*hb.z + w[4*k4+7]*hb.w;
    }
    float g = g0 + g1;
    // pytorch gate order i,f,g,o; wave-uniform activation select
    ga[j] = (j < 128 || j >= 192) ? fast_sig(g) : fast_tanh(g);
    __syncthreads();
    if (j < 64){
      c = ga[64+j]*c + ga[j]*ga[128+j];
      float hv = ga[192+j]*fast_tanh(c);
      h[j] = hv;
      out[t*64 + j] = hv;
    }
    xcur = xnext;
    __syncthreads();
  }
}

// ---------- cond_train = hf + hb_raw + ftr, row norms ----------
__global__ void k_cond(const float* condA, const float* condB, const float* ff,
                       float* cond, float* ncond){
  int t = blockIdx.x, j = threadIdx.x;   // 64 threads
  float v = condA[t*64+j] + condB[t*64+j] + ff[t*64+j];
  cond[t*64+j] = v;
  float s = v*v;
  #pragma unroll
  for (int off = 32; off; off >>= 1) s += __shfl_down(s, off);
  if (j == 0) ncond[t] = sqrtf(s);
}

// ---------- attention LSTM v4: 512 threads, cond register-resident -----------
// ALL private-array load loops fully unrolled: partial unroll (R6/R7's
// `#pragma unroll 8`) left runtime indices at SROA time, demoting wk/rows to
// scratch (VGPR_Count=92, ~640KB scratch traffic/step -> 7.3ms).
__global__ __launch_bounds__(512, 2) void k_attlstm(
        const float* cond, const float* Xatt, const float* ff,
        const void* whh, const void* ah0, const void* ac0, const void* ar0,
        float* ctest, const int* flag){
  __shared__ float hr[128];            // h | r
  __shared__ float gpart[512];
  __shared__ float pbuf[512*17];       // 34816 B
  __shared__ float rs2[4][32*17];      // 8704 B
  __shared__ float wred[16];           // [0..7] max, [8..15] sum
  int tid = threadIdx.x;
  bool f32 = flag[0] != 0;
  int j = tid & 255, half = tid >> 8;
  float wk[64];
  if (f32){
    const float* W = (const float*)whh + (size_t)half*64*256 + j;
    #pragma unroll
    for (int k = 0; k < 64; k++) wk[k] = W[k*256];
  } else {
    const uint16_t* W = (const uint16_t*)whh + (size_t)half*64*256 + j;
    #pragma unroll
    for (int k = 0; k < 64; k++) wk[k] = bf2f(W[k*256]);
  }
  float row0[64], row1[64];
  {
    const float4* r0 = (const float4*)(cond + (size_t)tid*64);
    const float4* r1 = (const float4*)(cond + (size_t)(tid+512)*64);
    #pragma unroll
    for (int k4 = 0; k4 < 16; k4++){
      float4 a = r0[k4]; float4 b = r1[k4];
      row0[4*k4]=a.x; row0[4*k4+1]=a.y; row0[4*k4+2]=a.z; row0[4*k4+3]=a.w;
      row1[4*k4]=b.x; row1[4*k4+1]=b.y; row1[4*k4+2]=b.z; row1[4*k4+3]=b.w;
    }
  }
  float c = 0.f;
  if (f32){
    if (tid < 64){ hr[tid] = ((const float*)ah0)[tid]; c = ((const float*)ac0)[tid]; }
    else if (tid < 128) hr[tid] = ((const float*)ar0)[tid-64];
  } else {
    if (tid < 64){ hr[tid] = bf2f(((const uint16_t*)ah0)[tid]); c = bf2f(((const uint16_t*)ac0)[tid]); }
    else if (tid < 128) hr[tid] = bf2f(((const uint16_t*)ar0)[tid-64]);
  }
  __syncthreads();
  int lane = tid & 63, wv = tid >> 6;
  const float* fte = ff + 65536;
  for (int st = 0; st < 1024; st++){
    // ---- phase 1: gate half-dots (all 512); 2 accumulators break dep chain ----
    float ga0 = (half == 0) ? Xatt[st*256 + j] : 0.f, ga1 = 0.f;
    {
      const float4* hc = (const float4*)(hr + half*64);
      #pragma unroll
      for (int k4 = 0; k4 < 16; k4 += 2){
        float4 hv = hc[k4];
        float4 hw = hc[k4+1];
        ga0 += wk[4*k4]*hv.x + wk[4*k4+1]*hv.y + wk[4*k4+2]*hv.z + wk[4*k4+3]*hv.w;
        ga1 += wk[4*k4+4]*hw.x + wk[4*k4+5]*hw.y + wk[4*k4+6]*hw.z + wk[4*k4+7]*hw.w;
      }
    }
    gpart[tid] = ga0 + ga1;
    __syncthreads();                                   // B1
    // ---- phase 2: wave 0 computes gates (order f,i,o,g) + cell ----
    if (tid < 64){
      float xres = fte[st*64 + tid];
      float gf = gpart[tid]     + gpart[256+tid];
      float gi = gpart[64+tid]  + gpart[320+tid];
      float go = gpart[128+tid] + gpart[384+tid];
      float gg = gpart[192+tid] + gpart[448+tid];
      float f_ = fast_sig(gf), i_ = fast_sig(gi), o_ = fast_sig(go), g_ = fast_tanh(gg);
      c = f_*c + i_*g_;
      float hv = o_*fast_tanh(c) + xres;
      hr[tid] = hv;
      ctest[st*64 + tid] = hv;
    }
    __syncthreads();                                   // B2
    // ---- QK from register rows (zero memory traffic for cond) ----
    float lg0a = 0.f, lg0b = 0.f, lg1a = 0.f, lg1b = 0.f;
    {
      const float4* hq = (const float4*)hr;
      #pragma unroll
      for (int k4 = 0; k4 < 16; k4 += 2){
        float4 hv = hq[k4];
        float4 hw = hq[k4+1];
        lg0a += row0[4*k4]*hv.x + row0[4*k4+1]*hv.y + row0[4*k4+2]*hv.z + row0[4*k4+3]*hv.w;
        lg0b += row0[4*k4+4]*hw.x + row0[4*k4+5]*hw.y + row0[4*k4+6]*hw.z + row0[4*k4+7]*hw.w;
        lg1a += row1[4*k4]*hv.x + row1[4*k4+1]*hv.y + row1[4*k4+2]*hv.z + row1[4*k4+3]*hv.w;
        lg1b += row1[4*k4+4]*hw.x + row1[4*k4+5]*hw.y + row1[4*k4+6]*hw.z + row1[4*k4+7]*hw.w;
      }
    }
    float lg0 = lg0a + lg0b, lg1 = lg1a + lg1b;
    // ---- softmax max ----
    float mx = fmaxf(lg0, lg1);
    #pragma unroll
    for (int off = 32; off; off >>= 1) mx = fmaxf(mx, __shfl_xor(mx, off));
    if (lane == 0) wred[wv] = mx;
    __syncthreads();                                   // B3
    float gmax = fmaxf(fmaxf(fmaxf(wred[0],wred[1]),fmaxf(wred[2],wred[3])),
                       fmaxf(fmaxf(wred[4],wred[5]),fmaxf(wred[6],wred[7])));
    float e0 = __expf(lg0 - gmax), e1 = __expf(lg1 - gmax);
    float s = e0 + e1;
    #pragma unroll
    for (int off = 32; off; off >>= 1) s += __shfl_xor(s, off);
    if (lane == 0) wred[8+wv] = s;
    __syncthreads();                                   // B4
    float inv = 1.f/(((wred[8]+wred[9])+(wred[10]+wred[11]))
                   + ((wred[12]+wred[13])+(wred[14]+wred[15])));
    // ---- AV: 4 chunks x 16 columns, exact fp32 LDS partial reduction ----
    #pragma unroll
    for (int ch = 0; ch < 4; ch++){
      #pragma unroll
      for (int k = 0; k < 16; k++)
        pbuf[tid*17 + k] = e0*row0[ch*16+k] + e1*row1[ch*16+k];
      __syncthreads();                                 // Bav-w
      {
        int kk = tid & 15, seg = tid >> 4;             // 32 segs x 16 rows
        float a = 0.f;
        #pragma unroll
        for (int q = 0; q < 16; q++)
          a += pbuf[(seg*16+q)*17 + kk];
        rs2[ch][seg*17 + kk] = a;
      }
      __syncthreads();                                 // Bav-r (pbuf reuse safe)
    }
    // ---- final r assembly by wave 0 ----
    if (tid < 64){
      int kk = lane & 15, chq = lane >> 4;             // column = chq*16+kk = lane
      float a = 0.f;
      #pragma unroll
      for (int sgm = 0; sgm < 32; sgm++) a += rs2[chq][sgm*17 + kk];
      hr[64 + lane] = a * inv;
    }
    __syncthreads();                                   // B-loop
  }
}

// ---------- final cosine-softmax label readout (output dtype follows sniff) ----
__global__ __launch_bounds__(256) void k_final(const float* ctest, const float* cond,
        const float* ncond, const void* labels, void* out, const int* flag){
  int t = blockIdx.x;
  __shared__ __align__(16) float q[64];
  __shared__ float sim[1024];
  __shared__ float red[4];
  __shared__ float accw[20];
  __shared__ float bcv[2];
  int tid = threadIdx.x;
  bool f32 = flag[0] != 0;
  if (tid < 64) q[tid] = ctest[t*64 + tid];
  if (tid < 20) accw[tid] = 0.f;
  __syncthreads();
  if (tid < 64){
    float s = q[tid]*q[tid];
    #pragma unroll
    for (int off = 32; off; off >>= 1) s += __shfl_down(s, off);
    if (tid == 0) bcv[0] = sqrtf(s);
  }
  __syncthreads();
  float nq = bcv[0];
  float mymax = -1e30f;
  for (int i = tid; i < 1024; i += 256){
    float d = 0.f;
    const float4* cr = (const float4*)(cond + i*64);
    #pragma unroll
    for (int k4 = 0; k4 < 16; k4++){
      float4 cv = cr[k4];
      float4 qv = ((const float4*)q)[k4];
      d += cv.x*qv.x + cv.y*qv.y + cv.z*qv.z + cv.w*qv.w;
    }
    float den = fmaxf(nq*ncond[i], 1e-8f);
    float sv = d/den;
    sim[i] = sv;
    mymax = fmaxf(mymax, sv);
  }
  int lane = tid & 63, wv = tid >> 6;
  #pragma unroll
  for (int off = 32; off; off >>= 1) mymax = fmaxf(mymax, __shfl_down(mymax, off));
  if (lane == 0) red[wv] = mymax;
  __syncthreads();
  if (tid == 0) bcv[1] = fmaxf(fmaxf(red[0], red[1]), fmaxf(red[2], red[3]));
  __syncthreads();
  float smax = bcv[1];
  float es = 0.f;
  float la[20];
  #pragma unroll
  for (int w = 0; w < 20; w++) la[w] = 0.f;
  if (f32){
    for (int i = tid; i < 1024; i += 256){
      float e = __expf(sim[i] - smax);
      es += e;
      const float* L = (const float*)labels + i*20;
      #pragma unroll
      for (int w = 0; w < 20; w++) la[w] += e*L[w];
    }
  } else {
    for (int i = tid; i < 1024; i += 256){
      float e = __expf(sim[i] - smax);
      es += e;
      const uint16_t* L = (const uint16_t*)labels + i*20;
      #pragma unroll
      for (int w = 0; w < 20; w++) la[w] += e*bf2f(L[w]);
    }
  }
  #pragma unroll
  for (int off = 32; off; off >>= 1) es += __shfl_down(es, off);
  if (lane == 0) red[wv] = es;
  #pragma unroll
  for (int w = 0; w < 20; w++) atomicAdd(&accw[w], la[w]);
  __syncthreads();
  if (tid == 0) bcv[0] = 1.f/(red[0] + red[1] + red[2] + red[3]);
  __syncthreads();
  if (tid < 20){
    float v = accw[tid]*bcv[0];
    if (f32) ((float*)out)[t*20 + tid] = v;
    else     ((uint16_t*)out)[t*20 + tid] = f2bf(v);
  }
}

// ---------- host launcher ----------
extern "C" void kernel_launch(void* const* d_in, const int* in_sizes, int n_in,
                              void* d_out, int out_size, void* d_ws, size_t ws_size,
                              hipStream_t stream){
  const void* trainIm    = d_in[0];
  const void* trainLabel = d_in[1];
  const void* testIm     = d_in[2];
  const void* c1w  = d_in[4];
  const void* c1b  = d_in[5];
  const void* bn1g = d_in[6];
  const void* bn1b = d_in[7];
  const void* c2w  = d_in[8];
  const void* c2b  = d_in[9];
  const void* bn2g = d_in[10];
  const void* bn2b = d_in[11];
  const void* c3w  = d_in[12];
  const void* c3b  = d_in[13];
  const void* bn3g = d_in[14];
  const void* bn3b = d_in[15];
  const void* wi_f = d_in[16];
  const void* wh_f = d_in[17];
  const void* bi_f = d_in[18];
  const void* bh_f = d_in[19];
  const void* wi_b = d_in[20];
  const void* wh_b = d_in[21];
  const void* bi_b = d_in[22];
  const void* bh_b = d_in[23];
  const void* h0   = d_in[24];
  const void* c0   = d_in[25];
  const void* att_wih = d_in[26];
  const void* att_whh = d_in[27];
  const void* att_b   = d_in[28];
  const void* att_h0  = d_in[29];
  const void* att_c0  = d_in[30];
  const void* att_r0  = d_in[31];

  char* ws = (char*)d_ws;
  float* stats = (float*)(ws + OFF_STATS);
  int*   flag  = (int*)(ws + OFF_FLAG);
  float* ab    = (float*)(ws + OFF_AB);
  float* p2raw = (float*)(ws + OFF_P2R);
  float* y3    = (float*)(ws + OFF_Y3);
  float* ff    = (float*)(ws + OFF_F);
  float* Xi    = (float*)(ws + OFF_XI);
  float* Xatt  = (float*)(ws + OFF_XATT);
  float* condA = (float*)(ws + OFF_CA);
  float* condB = (float*)(ws + OFF_CB);
  float* cond  = (float*)(ws + OFF_COND);
  float* ncond = (float*)(ws + OFF_NC);
  float* ctest = (float*)(ws + OFF_CT);

  k_sniff<<<1, 256, 0, stream>>>((const uint32_t*)trainIm, stats, flag);
  k_conv1_stats<<<2048, 256, 0, stream>>>(trainIm, testIm, c1w, c1b, stats, flag);
  k_bnfin<<<1, 192, 0, stream>>>(stats, ab, bn1g, bn1b, 0, 1.f/692224.f, flag);
  k_conv2<<<2048, 256, 0, stream>>>(trainIm, testIm, c1w, c1b, ab, c2w, c2b, p2raw, stats, flag);
  k_bnfin<<<1, 192, 0, stream>>>(stats, ab, bn2g, bn2b, 1, 1.f/123904.f, flag);
  k_conv3<<<256, 256, 0, stream>>>(p2raw, ab, c3w, c3b, y3, stats, flag);
  k_bnfin<<<1, 192, 0, stream>>>(stats, ab, bn3g, bn3b, 2, 1.f/9216.f, flag);
  k_pool3<<<512, 256, 0, stream>>>(y3, ab, ff);
  k_xproj<<<3072, 256, 0, stream>>>(ff, wi_f, bi_f, bh_f, wi_b, bi_b, bh_b, att_wih, att_b, Xi, Xatt, flag);
  k_bilstm<<<2, 256, 0, stream>>>(wh_f, wh_b, h0, c0, Xi, condA, condB, flag);
  k_cond<<<1024, 64, 0, stream>>>(condA, condB, ff, cond, ncond);
  k_attlstm<<<1, 512, 0, stream>>>(cond, Xatt, ff, att_whh, att_h0, att_c0, att_r0, ctest, flag);
  k_final<<<1024, 256, 0, stream>>>(ctest, cond, ncond, trainLabel, d_out, flag);
}